// Round 1
// baseline (308.295 us; speedup 1.0000x reference)
//
#include <hip/hip_runtime.h>
#include <stdint.h>

typedef unsigned short ushortT;
typedef __bf16 bf16x8 __attribute__((ext_vector_type(8)));
typedef float f32x4 __attribute__((ext_vector_type(4)));
typedef unsigned short ushort8 __attribute__((ext_vector_type(8)));

#define NPATCH 4096
#define MROWS  131072
#define CFEAT  176
#define KST    6                       // ksteps of 32 (K padded to 192)
#define TILE_USH 3072                  // one 16-row tile: 6 ksteps * 64 lanes * 8 bf16
#define TILE_BYTES 6144
#define MSPLIT 32
#define MCHUNK_TILES 256               // (131072/32)/16
#define MCHUNK_BYTES (MCHUNK_TILES * TILE_BYTES)   // 1572864
#define BN_TILES 4                     // 64 memory rows per iteration
#define ITER_BYTES (BN_TILES * TILE_BYTES)         // 24576
#define ITERS (MCHUNK_TILES / BN_TILES)            // 64

__device__ __forceinline__ ushortT f2bf(float f) {
    unsigned u = __float_as_uint(f);
    unsigned r = (u + 0x7FFFu + ((u >> 16) & 1u)) >> 16;   // RNE
    return (ushortT)r;
}
__device__ __forceinline__ unsigned f2key(float f) {
    unsigned b = __float_as_uint(f);
    return (b & 0x80000000u) ? ~b : (b | 0x80000000u);     // monotone order-preserving map
}
__device__ __forceinline__ float key2f(unsigned k) {
    return __uint_as_float((k & 0x80000000u) ? (k ^ 0x80000000u) : ~k);
}

// Normalize 64 rows per block; write bf16 in MFMA fragment order:
// frag[tile][kstep][lane][j] = row (tile*16 + lane%16), k = kstep*32 + (lane/16)*8 + j  (0 if k>=176)
__global__ __launch_bounds__(256) void nrmfrag(const float* __restrict__ in,
                                               ushortT* __restrict__ outfr) {
    __shared__ float scale[64];
    const int t = threadIdx.x;
    const int row0 = blockIdx.x * 64;
    {   // phase 1: 4 threads per row compute 1/(||x||+eps)
        const int r = t >> 2, part = t & 3;
        const float4* rp4 = reinterpret_cast<const float4*>(in + (size_t)(row0 + r) * CFEAT + part * 44);
        float s = 0.f;
#pragma unroll
        for (int i = 0; i < 11; ++i) {
            float4 v = rp4[i];
            s += v.x * v.x + v.y * v.y + v.z * v.z + v.w * v.w;
        }
        s += __shfl_xor(s, 1);
        s += __shfl_xor(s, 2);
        if (part == 0) scale[r] = 1.0f / (sqrtf(s) + 1e-6f);
    }
    __syncthreads();
    // phase 2: scale + pack to fragment layout (coalesced 16B stores)
    const int tl = t >> 6;             // local tile 0..3
    const int lane = t & 63;
    const int col = lane & 15, kh = lane >> 4;
    const int lrow = tl * 16 + col;
    const float* rp = in + (size_t)(row0 + lrow) * CFEAT;
    const float sc = scale[lrow];
    const size_t tile = (size_t)(row0 >> 4) + tl;
#pragma unroll
    for (int ks = 0; ks < KST; ++ks) {
        const int kb = ks * 32 + kh * 8;
        ushort8 o;
        if (kb < CFEAT) {  // groups of 8 are either fully in-range or fully pad
            const float4* v4 = reinterpret_cast<const float4*>(rp + kb);
            float4 v0 = v4[0], v1 = v4[1];
            o[0] = f2bf(v0.x * sc); o[1] = f2bf(v0.y * sc);
            o[2] = f2bf(v0.z * sc); o[3] = f2bf(v0.w * sc);
            o[4] = f2bf(v1.x * sc); o[5] = f2bf(v1.y * sc);
            o[6] = f2bf(v1.z * sc); o[7] = f2bf(v1.w * sc);
        } else {
#pragma unroll
            for (int j = 0; j < 8; ++j) o[j] = 0;
        }
        *reinterpret_cast<ushort8*>(outfr + (tile * KST + ks) * (size_t)512 + lane * 8) = o;
    }
}

__global__ void initkeys(unsigned* keys) { keys[blockIdx.x * 256 + threadIdx.x] = 0u; }

// Max-reduced GEMM: out max_sim over memory rows. A panel (64 rows/wave) in registers,
// B streamed through double-buffered LDS via global_load_lds (width 16), frag-order layout.
__global__ __launch_bounds__(256, 2) void gemm_max(const ushortT* __restrict__ pfr,
                                                   const ushortT* __restrict__ mfr,
                                                   unsigned* __restrict__ keys) {
    __shared__ ushortT lds[2][ITER_BYTES / 2];
    const int t = threadIdx.x;
    const int w = t >> 6;
    const int lane = t & 63;
    const int mchunk = blockIdx.x;
    const int panel = blockIdx.y;

    // A fragments: 4 m-tiles x 6 ksteps, held in registers for entire kernel
    bf16x8 a[4][KST];
    {
        const int ptile0 = panel * 16 + w * 4;
#pragma unroll
        for (int m = 0; m < 4; ++m)
#pragma unroll
            for (int k = 0; k < KST; ++k)
                a[m][k] = *reinterpret_cast<const bf16x8*>(
                    pfr + ((size_t)(ptile0 + m) * KST + k) * 512 + lane * 8);
    }

    float runmax[4][4];
#pragma unroll
    for (int m = 0; m < 4; ++m)
#pragma unroll
        for (int r = 0; r < 4; ++r) runmax[m][r] = -3.0e38f;

    const uint8_t* gbase = reinterpret_cast<const uint8_t*>(mfr) + (size_t)mchunk * MCHUNK_BYTES;

    auto stage = [&](int buf, int it) {
        const uint8_t* src = gbase + (size_t)it * ITER_BYTES + w * 6144 + lane * 16;
        uint8_t* dstb = reinterpret_cast<uint8_t*>(&lds[buf][0]) + w * 6144;
#pragma unroll
        for (int i = 0; i < 6; ++i) {
            __builtin_amdgcn_global_load_lds(
                (const __attribute__((address_space(1))) unsigned int*)(src + i * 1024),
                (__attribute__((address_space(3))) unsigned int*)(dstb + i * 1024),
                16, 0, 0);
        }
    };

    stage(0, 0);
    int cur = 0;
    for (int it = 0; it < ITERS; ++it) {
        if (it + 1 < ITERS) {
            stage(cur ^ 1, it + 1);
            asm volatile("s_waitcnt vmcnt(6)" ::: "memory");  // current buffer's 6 loads done
        } else {
            asm volatile("s_waitcnt vmcnt(0)" ::: "memory");
        }
        __syncthreads();

        const ushortT* lb = &lds[cur][0];
#pragma unroll
        for (int n = 0; n < BN_TILES; ++n) {
            bf16x8 b[KST];
#pragma unroll
            for (int k = 0; k < KST; ++k)
                b[k] = *reinterpret_cast<const bf16x8*>(lb + (n * KST + k) * 512 + lane * 8);
            f32x4 acc[4];
#pragma unroll
            for (int m = 0; m < 4; ++m) acc[m] = f32x4{0.f, 0.f, 0.f, 0.f};
#pragma unroll
            for (int k = 0; k < KST; ++k)
#pragma unroll
                for (int m = 0; m < 4; ++m)
                    acc[m] = __builtin_amdgcn_mfma_f32_16x16x32_bf16(a[m][k], b[k], acc[m], 0, 0, 0);
#pragma unroll
            for (int m = 0; m < 4; ++m)
#pragma unroll
                for (int r = 0; r < 4; ++r)
                    runmax[m][r] = fmaxf(runmax[m][r], acc[m][r]);
        }
        __syncthreads();
        cur ^= 1;
    }

    // reduce max across the 16 col-lanes of each group; lane%16==0 holds row result
#pragma unroll
    for (int m = 0; m < 4; ++m) {
#pragma unroll
        for (int r = 0; r < 4; ++r) {
            float v = runmax[m][r];
            v = fmaxf(v, __shfl_xor(v, 1));
            v = fmaxf(v, __shfl_xor(v, 2));
            v = fmaxf(v, __shfl_xor(v, 4));
            v = fmaxf(v, __shfl_xor(v, 8));
            if ((lane & 15) == 0) {
                int prow = panel * 256 + w * 64 + m * 16 + (lane >> 4) * 4 + r;
                atomicMax(&keys[prow], f2key(v));
            }
        }
    }
}

// decode keys -> patch scores; iterative top-k (k from device) -> mean
__global__ __launch_bounds__(256) void finalize(const unsigned* __restrict__ keys,
                                                const int* __restrict__ topk_p,
                                                float* __restrict__ out) {
    __shared__ float s[NPATCH];
    __shared__ float rv[256];
    __shared__ int ri[256];
    const int t = threadIdx.x;
    for (int i = t; i < NPATCH; i += 256) {
        float score = 1.0f - key2f(keys[i]);
        out[i] = score;
        s[i] = score;
    }
    __syncthreads();
    const int K = *topk_p;
    float sum = 0.f;
    for (int it = 0; it < K; ++it) {
        float bv = -3.0e38f; int bi = -1;
        for (int i = t; i < NPATCH; i += 256)
            if (s[i] > bv) { bv = s[i]; bi = i; }
        rv[t] = bv; ri[t] = bi;
        __syncthreads();
        for (int off = 128; off > 0; off >>= 1) {
            if (t < off && rv[t + off] > rv[t]) { rv[t] = rv[t + off]; ri[t] = ri[t + off]; }
            __syncthreads();
        }
        if (t == 0) { sum += rv[0]; s[ri[0]] = -3.0e38f; }
        __syncthreads();
    }
    if (t == 0) out[NPATCH] = sum / (float)K;
}

extern "C" void kernel_launch(void* const* d_in, const int* in_sizes, int n_in,
                              void* d_out, int out_size, void* d_ws, size_t ws_size,
                              hipStream_t stream) {
    (void)in_sizes; (void)n_in; (void)out_size; (void)ws_size;
    const float* patch = (const float*)d_in[0];
    const float* mem   = (const float*)d_in[1];
    const int*   topk  = (const int*)d_in[2];
    float* out = (float*)d_out;

    uint8_t* ws = (uint8_t*)d_ws;
    ushortT*  mfr  = (ushortT*)ws;                                   // 50,331,648 B
    ushortT*  pfr  = (ushortT*)(ws + 50331648);                      //  1,572,864 B
    unsigned* keys = (unsigned*)(ws + 50331648 + 1572864);           //     16,384 B

    nrmfrag<<<MROWS / 64, 256, 0, stream>>>(mem, mfr);
    nrmfrag<<<NPATCH / 64, 256, 0, stream>>>(patch, pfr);
    initkeys<<<NPATCH / 256, 256, 0, stream>>>(keys);
    gemm_max<<<dim3(MSPLIT, NPATCH / 256), 256, 0, stream>>>(pfr, mfr, keys);
    finalize<<<1, 256, 0, stream>>>(keys, topk, out);
}

// Round 2
// 305.678 us; speedup vs baseline: 1.0086x; 1.0086x over previous
//
#include <hip/hip_runtime.h>
#include <stdint.h>

typedef unsigned short ushortT;
typedef __bf16 bf16x8 __attribute__((ext_vector_type(8)));
typedef float f32x4 __attribute__((ext_vector_type(4)));
typedef unsigned short ushort8 __attribute__((ext_vector_type(8)));

#define NPATCH 4096
#define MROWS  131072
#define CFEAT  176
#define KST    6                       // ksteps of 32 (K padded to 192)
#define TILE_BYTES 6144
#define MSPLIT 32
#define MCHUNK_TILES 256               // (131072/32)/16
#define MCHUNK_BYTES (MCHUNK_TILES * TILE_BYTES)   // 1572864
#define BN_TILES 4                     // 64 memory rows per iteration
#define ITER_BYTES (BN_TILES * TILE_BYTES)         // 24576
#define ITERS (MCHUNK_TILES / BN_TILES)            // 64
#define LROW 180                       // padded LDS row stride (floats); 720B, 16B-aligned

__device__ __forceinline__ ushortT f2bf(float f) {
    unsigned u = __float_as_uint(f);
    unsigned r = (u + 0x7FFFu + ((u >> 16) & 1u)) >> 16;   // RNE
    return (ushortT)r;
}
__device__ __forceinline__ unsigned f2key(float f) {
    unsigned b = __float_as_uint(f);
    return (b & 0x80000000u) ? ~b : (b | 0x80000000u);     // monotone order-preserving map
}
__device__ __forceinline__ float key2f(unsigned k) {
    return __uint_as_float((k & 0x80000000u) ? (k ^ 0x80000000u) : ~k);
}

// Normalize 64 rows per block; write bf16 in MFMA fragment order.
// Round 2: stage the contiguous 64x176 fp32 block into LDS with coalesced float4
// streaming reads; norms + fragment packing then read LDS (padded stride, <=2-way).
__global__ __launch_bounds__(256) void nrmfrag(const float* __restrict__ in,
                                               ushortT* __restrict__ outfr) {
    __shared__ float buf[64 * LROW];   // 46080 B
    __shared__ float scale[64];
    const int t = threadIdx.x;
    const int row0 = blockIdx.x * 64;

    // stage: 64*176 floats = 2816 float4, contiguous in global, padded rows in LDS
    const float4* g4 = reinterpret_cast<const float4*>(in + (size_t)row0 * CFEAT);
#pragma unroll
    for (int i = 0; i < 11; ++i) {
        const int idx = i * 256 + t;           // 0..2815
        const int row = idx / 44;              // 44 float4 per row
        const int c4  = idx - row * 44;
        float4 v = g4[idx];
        *reinterpret_cast<float4*>(&buf[row * LROW + c4 * 4]) = v;
    }
    __syncthreads();

    {   // norms: 4 threads per row, from LDS
        const int r = t >> 2, part = t & 3;
        const float* rp = &buf[r * LROW + part * 44];
        float s = 0.f;
#pragma unroll
        for (int i = 0; i < 11; ++i) {
            float4 v = *reinterpret_cast<const float4*>(rp + i * 4);
            s += v.x * v.x + v.y * v.y + v.z * v.z + v.w * v.w;
        }
        s += __shfl_xor(s, 1);
        s += __shfl_xor(s, 2);
        if (part == 0) scale[r] = 1.0f / (sqrtf(s) + 1e-6f);
    }
    __syncthreads();

    // pack to fragment layout (coalesced 16B stores)
    const int tl = t >> 6;             // local tile 0..3
    const int lane = t & 63;
    const int col = lane & 15, kh = lane >> 4;
    const int lrow = tl * 16 + col;
    const float* rp = &buf[lrow * LROW];
    const float sc = scale[lrow];
    const size_t tile = (size_t)(row0 >> 4) + tl;
#pragma unroll
    for (int ks = 0; ks < KST; ++ks) {
        const int kb = ks * 32 + kh * 8;
        ushort8 o;
        if (kb < CFEAT) {  // groups of 8 are either fully in-range or fully pad
            float4 v0 = *reinterpret_cast<const float4*>(rp + kb);
            float4 v1 = *reinterpret_cast<const float4*>(rp + kb + 4);
            o[0] = f2bf(v0.x * sc); o[1] = f2bf(v0.y * sc);
            o[2] = f2bf(v0.z * sc); o[3] = f2bf(v0.w * sc);
            o[4] = f2bf(v1.x * sc); o[5] = f2bf(v1.y * sc);
            o[6] = f2bf(v1.z * sc); o[7] = f2bf(v1.w * sc);
        } else {
#pragma unroll
            for (int j = 0; j < 8; ++j) o[j] = 0;
        }
        *reinterpret_cast<ushort8*>(outfr + (tile * KST + ks) * (size_t)512 + lane * 8) = o;
    }
}

__global__ void initkeys(unsigned* keys) { keys[blockIdx.x * 256 + threadIdx.x] = 0u; }

// Max-reduced GEMM. Round 2: raw s_barrier (no implicit vmcnt(0) drain),
// ONE barrier per iteration, vmcnt(0) only after the full compute phase.
__global__ __launch_bounds__(256, 2) void gemm_max(const ushortT* __restrict__ pfr,
                                                   const ushortT* __restrict__ mfr,
                                                   unsigned* __restrict__ keys) {
    __shared__ ushortT lds[2][ITER_BYTES / 2];
    const int t = threadIdx.x;
    const int w = t >> 6;
    const int lane = t & 63;
    const int mchunk = blockIdx.x;
    const int panel = blockIdx.y;

    // A fragments: 4 m-tiles x 6 ksteps, held in registers for entire kernel
    bf16x8 a[4][KST];
    {
        const int ptile0 = panel * 16 + w * 4;
#pragma unroll
        for (int m = 0; m < 4; ++m)
#pragma unroll
            for (int k = 0; k < KST; ++k)
                a[m][k] = *reinterpret_cast<const bf16x8*>(
                    pfr + ((size_t)(ptile0 + m) * KST + k) * 512 + lane * 8);
    }

    float runmax[4][4];
#pragma unroll
    for (int m = 0; m < 4; ++m)
#pragma unroll
        for (int r = 0; r < 4; ++r) runmax[m][r] = -3.0e38f;

    const uint8_t* gbase = reinterpret_cast<const uint8_t*>(mfr) + (size_t)mchunk * MCHUNK_BYTES;

    auto stage = [&](int buf, int it) {
        const uint8_t* src = gbase + (size_t)it * ITER_BYTES + w * 6144 + lane * 16;
        uint8_t* dstb = reinterpret_cast<uint8_t*>(&lds[buf][0]) + w * 6144;
#pragma unroll
        for (int i = 0; i < 6; ++i) {
            __builtin_amdgcn_global_load_lds(
                (const __attribute__((address_space(1))) unsigned int*)(src + i * 1024),
                (__attribute__((address_space(3))) unsigned int*)(dstb + i * 1024),
                16, 0, 0);
        }
    };

    // prologue: stage tile 0, drain own loads, sync all waves
    stage(0, 0);
    asm volatile("s_waitcnt vmcnt(0)" ::: "memory");
    __builtin_amdgcn_s_barrier();

    int cur = 0;
    for (int it = 0; it < ITERS; ++it) {
        if (it + 1 < ITERS) stage(cur ^ 1, it + 1);   // issue prefetch FIRST

        const ushortT* lb = &lds[cur][0];
#pragma unroll
        for (int n = 0; n < BN_TILES; ++n) {
            bf16x8 b[KST];
#pragma unroll
            for (int k = 0; k < KST; ++k)
                b[k] = *reinterpret_cast<const bf16x8*>(lb + (n * KST + k) * 512 + lane * 8);
            f32x4 acc[4];
#pragma unroll
            for (int m = 0; m < 4; ++m) acc[m] = f32x4{0.f, 0.f, 0.f, 0.f};
#pragma unroll
            for (int k = 0; k < KST; ++k)
#pragma unroll
                for (int m = 0; m < 4; ++m)
                    acc[m] = __builtin_amdgcn_mfma_f32_16x16x32_bf16(a[m][k], b[k], acc[m], 0, 0, 0);
#pragma unroll
            for (int m = 0; m < 4; ++m)
#pragma unroll
                for (int r = 0; r < 4; ++r)
                    runmax[m][r] = fmaxf(runmax[m][r], acc[m][r]);
        }

        // prefetch (issued ~3700 cycles ago) lands here; one barrier per iter.
        asm volatile("s_waitcnt vmcnt(0)" ::: "memory");
        __builtin_amdgcn_s_barrier();
        cur ^= 1;
    }

    // reduce max across the 16 col-lanes of each group; lane%16==0 holds row result
#pragma unroll
    for (int m = 0; m < 4; ++m) {
#pragma unroll
        for (int r = 0; r < 4; ++r) {
            float v = runmax[m][r];
            v = fmaxf(v, __shfl_xor(v, 1));
            v = fmaxf(v, __shfl_xor(v, 2));
            v = fmaxf(v, __shfl_xor(v, 4));
            v = fmaxf(v, __shfl_xor(v, 8));
            if ((lane & 15) == 0) {
                int prow = panel * 256 + w * 64 + m * 16 + (lane >> 4) * 4 + r;
                atomicMax(&keys[prow], f2key(v));
            }
        }
    }
}

// decode keys -> patch scores; iterative top-k (k from device) -> mean
__global__ __launch_bounds__(256) void finalize(const unsigned* __restrict__ keys,
                                                const int* __restrict__ topk_p,
                                                float* __restrict__ out) {
    __shared__ float s[NPATCH];
    __shared__ float rv[256];
    __shared__ int ri[256];
    const int t = threadIdx.x;
    for (int i = t; i < NPATCH; i += 256) {
        float score = 1.0f - key2f(keys[i]);
        out[i] = score;
        s[i] = score;
    }
    __syncthreads();
    const int K = *topk_p;
    float sum = 0.f;
    for (int it = 0; it < K; ++it) {
        float bv = -3.0e38f; int bi = -1;
        for (int i = t; i < NPATCH; i += 256)
            if (s[i] > bv) { bv = s[i]; bi = i; }
        rv[t] = bv; ri[t] = bi;
        __syncthreads();
        for (int off = 128; off > 0; off >>= 1) {
            if (t < off && rv[t + off] > rv[t]) { rv[t] = rv[t + off]; ri[t] = ri[t + off]; }
            __syncthreads();
        }
        if (t == 0) { sum += rv[0]; s[ri[0]] = -3.0e38f; }
        __syncthreads();
    }
    if (t == 0) out[NPATCH] = sum / (float)K;
}

extern "C" void kernel_launch(void* const* d_in, const int* in_sizes, int n_in,
                              void* d_out, int out_size, void* d_ws, size_t ws_size,
                              hipStream_t stream) {
    (void)in_sizes; (void)n_in; (void)out_size; (void)ws_size;
    const float* patch = (const float*)d_in[0];
    const float* mem   = (const float*)d_in[1];
    const int*   topk  = (const int*)d_in[2];
    float* out = (float*)d_out;

    uint8_t* ws = (uint8_t*)d_ws;
    ushortT*  mfr  = (ushortT*)ws;                                   // 50,331,648 B
    ushortT*  pfr  = (ushortT*)(ws + 50331648);                      //  1,572,864 B
    unsigned* keys = (unsigned*)(ws + 50331648 + 1572864);           //     16,384 B

    nrmfrag<<<MROWS / 64, 256, 0, stream>>>(mem, mfr);
    nrmfrag<<<NPATCH / 64, 256, 0, stream>>>(patch, pfr);
    initkeys<<<NPATCH / 256, 256, 0, stream>>>(keys);
    gemm_max<<<dim3(MSPLIT, NPATCH / 256), 256, 0, stream>>>(pfr, mfr, keys);
    finalize<<<1, 256, 0, stream>>>(keys, topk, out);
}